// Round 5
// baseline (1756.083 us; speedup 1.0000x reference)
//
#include <hip/hip_runtime.h>

// NeuralODE: B=1024, D=64, F=8, H=256, 196 substeps x 6 dopri5 stages.
// R14: R13 body + launch_bounds(256,1) -- occupancy via REGISTER COUNT,
// not directives. Evidence: (256,1)->120reg clean, (256,2)->96 clean,
// (256,4)->64+48spill, waves_per_eu(4,4)->64+22spill. Both "4 waves/EU"
// spellings made the backend clamp to the 8-wave 64-reg budget and spill
// (WRITE_SIZE 12.8->62/35MB). R14: demand ~110 regs < 128-reg cliff, so
// with (256,1) the allocator picks ~110 and HW gives 4 waves/SIMD =
// 4 blocks/CU (pool halves at 64/128/256) with zero scratch.
// Structure (from R13):
//  - 1024 blocks x 256 thr, 1 row/block; zAh/hAh zeroed once (pad rows 0).
//  - GEMM1: wave owns N-tiles wv*4+t, x-part K=64 in fp16 regs (b1h 32r),
//    u-part as rank-8 fp32 VALU dot (w1u 8r) + __shfl; 8 MFMAs/stage.
//  - GEMM2: wave owns N-tile wv, full K=256 (b2h 32r), 8 MFMAs, D-layout
//    == state layout -> k in regs, no reduce.
//  - 2 barriers/stage + u-interp barrier per substep.
// Numerics: W1/W2 hi fp16 (W1 prescaled 2*log2e), u fp32, fp32 state,
// tanh = 1 - 2*rcp(exp2(y)+1); absmax floor 0.0156.
// MFMA layouts (HW-verified R7/R8): A[m=l&15][k=(l>>4)*8+j],
//   B[k=(l>>4)*8+j][n=l&15], D[row=(l>>4)*4+reg][col=l&15].
// A-frag LDS planes [k>>3][m][k&7], stride 144 halves (288B); wave64 b128
// reads are 8-access/bank (structural floor for 1KB/instr).

typedef _Float16 half8 __attribute__((ext_vector_type(8)));
typedef float f32x4 __attribute__((ext_vector_type(4)));

#define MFMA16(a, b, c) __builtin_amdgcn_mfma_f32_16x16x32_f16((a), (b), (c), 0, 0, 0)

__global__ __launch_bounds__(256, 1)
void node_kernel(const float* __restrict__ x0,
                 const float* __restrict__ t_eval,
                 const float* __restrict__ t_u,
                 const float* __restrict__ u_batch,
                 const float* __restrict__ W1,
                 const float* __restrict__ b1,
                 const float* __restrict__ W2,
                 const float* __restrict__ b2,
                 float* __restrict__ out)
{
    __shared__ __align__(16) _Float16 zAh[8 * 144];    // z x-part, K=64
    __shared__ __align__(16) _Float16 hAh[32 * 144];   // h, K=256
    __shared__ __align__(16) float ush[6][8];          // interp u per stage

    const int tid = threadIdx.x;
    const int wv  = tid >> 6;        // wave 0..3
    const int l   = tid & 63;
    const int lm  = l & 15;
    const int lq  = l >> 4;
    const int blk = blockIdx.x;

    const float C2L = 2.8853900817779268f;   // 2*log2(e)

    // --- zero zAh/hAh once: padding rows stay 0 forever ---
    for (int i = tid; i < (8 * 144) / 2; i += 256)  ((uint32_t*)zAh)[i] = 0u;
    for (int i = tid; i < (32 * 144) / 2; i += 256) ((uint32_t*)hAh)[i] = 0u;

    // --- GEMM1 B-frags: wave owns N-tiles wv*4+t, x-part K=64 only ---
    half8 b1h[4][2];
    float b1b[4];
#pragma unroll
    for (int t = 0; t < 4; ++t) {
        const int n1 = (wv * 4 + t) * 16 + lm;
        b1b[t] = b1[n1] * C2L;
#pragma unroll
        for (int c = 0; c < 2; ++c) {
#pragma unroll
            for (int j = 0; j < 8; ++j) {
                const int k = c * 32 + lq * 8 + j;
                b1h[t][c][j] = (_Float16)(W1[k * 256 + n1] * C2L);
            }
        }
    }
    // --- u-part weights: lane l holds W1u[f][wv*64+l], f=0..7 (fp32) ---
    const int n1u = wv * 64 + l;
    float w1u[8];
#pragma unroll
    for (int f = 0; f < 8; ++f)
        w1u[f] = W1[(64 + f) * 256 + n1u] * C2L;

    // --- GEMM2 B-frags: wave owns N-tile wv, FULL K=256 ---
    const int n2 = wv * 16 + lm;
    half8 b2h[8];
#pragma unroll
    for (int cc = 0; cc < 8; ++cc) {
#pragma unroll
        for (int j = 0; j < 8; ++j) {
            const int k = cc * 32 + lq * 8 + j;
            b2h[cc][j] = (_Float16)W2[k * 64 + n2];
        }
    }
    const float b2b = b2[n2];

    // --- ODE state: 1 row (tile row 0 <-> lq==0, reg 0). All lanes carry
    //     copies; only lq==0 lanes publish. ---
    float xr = x0[blk * 64 + n2];
    float kfr[5];
    if (lq == 0) out[blk * 3200 + n2] = xr;      // t_eval[0]
    __syncthreads();   // zero-init visible

#pragma unroll 1
    for (int step = 0; step < 196; ++step) {
        const int n = step >> 2;
        const int m = step & 3;
        const float te0 = t_eval[n];
        const float dtc = t_eval[n + 1] - te0;
        const float t   = te0 + dtc * (0.25f * (float)m);
        const float dt  = dtc * 0.25f;

        // --- u prefetch+interp: 48 slots (6 stages x 8 feats) ---
        if (tid < 48) {
            const int s = tid >> 3;
            const int f = tid & 7;
            float cs;
            switch (s) {
                case 0: cs = 0.0f; break;
                case 1: cs = 1.0f / 5.0f; break;
                case 2: cs = 3.0f / 10.0f; break;
                case 3: cs = 4.0f / 5.0f; break;
                case 4: cs = 8.0f / 9.0f; break;
                default: cs = 1.0f; break;
            }
            const float tsv = t + dt * cs;
            int iu = (int)(tsv * 127.0f);       // == searchsorted-1
            iu = iu < 0 ? 0 : (iu > 126 ? 126 : iu);
            const float ta = t_u[iu];
            const float tb = t_u[iu + 1];
            const float wt = (tsv - ta) / (tb - ta);
            const float* ub = &u_batch[blk * 1024 + iu * 8 + f];
            const float u0v = ub[0];
            const float u1v = ub[8];
            ush[s][f] = fmaf(wt, u1v - u0v, u0v);
        }
        __syncthreads();   // B0: ush ready

#pragma unroll
        for (int s = 0; s < 6; ++s) {
            // --- z x-part, row 0 (combine in all lanes, lq==0 writes) ---
            float zv;
            if (s == 0)      zv = xr;
            else if (s == 1) zv = fmaf(dt, kfr[0] * (1.0f/5.0f), xr);
            else if (s == 2) zv = fmaf(dt, fmaf(3.0f/40.0f, kfr[0], (9.0f/40.0f)*kfr[1]), xr);
            else if (s == 3) zv = fmaf(dt, (44.0f/45.0f)*kfr[0] + (-56.0f/15.0f)*kfr[1]
                                          + (32.0f/9.0f)*kfr[2], xr);
            else if (s == 4) zv = fmaf(dt, (19372.0f/6561.0f)*kfr[0] + (-25360.0f/2187.0f)*kfr[1]
                                          + (64448.0f/6561.0f)*kfr[2] + (-212.0f/729.0f)*kfr[3], xr);
            else             zv = fmaf(dt, (9017.0f/3168.0f)*kfr[0] + (-355.0f/33.0f)*kfr[1]
                                          + (46732.0f/5247.0f)*kfr[2] + (49.0f/176.0f)*kfr[3]
                                          + (-5103.0f/18656.0f)*kfr[4], xr);
            if (lq == 0)
                zAh[(n2 >> 3) * 144 + (n2 & 7)] = (_Float16)zv;
            __syncthreads();   // B1: z ready

            // --- u-part rank-8 dot: y_u for n1 = wv*64 + l (all 64 cols) ---
            const float4 uA = *(const float4*)&ush[s][0];
            const float4 uB = *(const float4*)&ush[s][4];
            float yu = uA.x * w1u[0];
            yu = fmaf(uA.y, w1u[1], yu);
            yu = fmaf(uA.z, w1u[2], yu);
            yu = fmaf(uA.w, w1u[3], yu);
            yu = fmaf(uB.x, w1u[4], yu);
            yu = fmaf(uB.y, w1u[5], yu);
            yu = fmaf(uB.z, w1u[6], yu);
            yu = fmaf(uB.w, w1u[7], yu);

            // --- GEMM1: 2 A-reads, 4 N-tiles, 8 MFMAs ---
            half8 az[2];
#pragma unroll
            for (int c = 0; c < 2; ++c)
                az[c] = *(const half8*)&zAh[(c * 4 + lq) * 144 + lm * 8];
#pragma unroll
            for (int t = 0; t < 4; ++t) {
                f32x4 aHH = {0.f, 0.f, 0.f, 0.f};
                aHH = MFMA16(az[0], b1h[t][0], aHH);
                aHH = MFMA16(az[1], b1h[t][1], aHH);
                const float yut = __shfl(yu, t * 16 + lm);
                const int kqb = (wv * 4 + t) * 2 + (lm >> 3);   // h-col>>3 plane
                // tanh only on row 0 (reg 0; valid in lq==0 lanes)
                const float y = aHH[0] + yut + b1b[t];           // 2log2e*(zW1+b1)
                const float e = __builtin_amdgcn_exp2f(y);
                const float hv = fmaf(-2.0f, __builtin_amdgcn_rcpf(e + 1.0f), 1.0f);
                if (lq == 0)
                    hAh[kqb * 144 + (lm & 7)] = (_Float16)hv;
            }
            __syncthreads();   // B2: h ready

            // --- GEMM2: full K=256, 8 MFMAs in 2 dep-chains of 4 ---
            f32x4 aP = {0.f, 0.f, 0.f, 0.f};
            f32x4 aR = {0.f, 0.f, 0.f, 0.f};
#pragma unroll
            for (int cc = 0; cc < 8; cc += 2) {
                const half8 ah0 = *(const half8*)&hAh[((cc    ) * 4 + lq) * 144 + lm * 8];
                const half8 ah1 = *(const half8*)&hAh[((cc + 1) * 4 + lq) * 144 + lm * 8];
                aP = MFMA16(ah0, b2h[cc    ], aP);
                aR = MFMA16(ah1, b2h[cc + 1], aR);
            }
            if (s < 5) {
                kfr[s] = (aP[0] + aR[0]) + b2b;
            } else {
                const float k6 = (aP[0] + aR[0]) + b2b;
                xr = fmaf(dt, (35.0f/384.0f)*kfr[0] + (500.0f/1113.0f)*kfr[2]
                             + (125.0f/192.0f)*kfr[3] + (-2187.0f/6784.0f)*kfr[4]
                             + (11.0f/84.0f)*k6, xr);
            }
        }

        // --- output every 4th substep ---
        if (m == 3 && lq == 0)
            out[blk * 3200 + (n + 1) * 64 + n2] = xr;
    }
}

extern "C" void kernel_launch(void* const* d_in, const int* in_sizes, int n_in,
                              void* d_out, int out_size, void* d_ws, size_t ws_size,
                              hipStream_t stream) {
    const float* x0      = (const float*)d_in[0];
    const float* t_eval  = (const float*)d_in[1];
    const float* t_u     = (const float*)d_in[2];
    const float* u_batch = (const float*)d_in[3];
    const float* W1      = (const float*)d_in[4];
    const float* b1      = (const float*)d_in[5];
    const float* W2      = (const float*)d_in[6];
    const float* b2      = (const float*)d_in[7];
    float* out = (float*)d_out;

    node_kernel<<<dim3(1024), dim3(256), 0, stream>>>(
        x0, t_eval, t_u, u_batch, W1, b1, W2, b2, out);
}

// Round 6
// 1160.146 us; speedup vs baseline: 1.5137x; 1.5137x over previous
//
#include <hip/hip_runtime.h>

// NeuralODE: B=1024, D=64, F=8, H=256, 196 substeps x 6 dopri5 stages.
// R15: lean body repacked into the proven-resident grid. 512 blocks x 256
// threads, 2 rows/block, launch_bounds(256,2) -- the ONE config verified
// clean (R11: 96 arch regs, no spill, all blocks co-resident at 2/CU).
// R14 post-mortem: gfx950 unified VGPR/AGPR file -- rocprof VGPR_Count is
// arch-only; frags (~72) live in AGPRs, true per-wave alloc ~160-170 ->
// 4 blocks/CU unreachable; 1024 blocks ran as TWO sequential rounds of
// 512. Per-round 926us => lean-body stage = 1890cyc @ 2 blocks/CU (vs
// 2450 for R11's fat body) -- lean body confirmed, packing wasted it.
// R15 = R11 grid + R13/R14 lean body:
//  - GEMM1: wave owns N-tiles wv*4+t, x-part K=64 fp16 frags (b1h 32r),
//    u-part = rank-8 fp32 VALU dot (w1u 8r) + __shfl per tile; 8 MFMAs.
//  - GEMM2: wave owns N-tile wv, full K=256 (b2h 32r), 8 MFMAs, D-layout
//    == state layout -> k direct in regs, no reduce.
//  - 2 barriers/stage; zAh x-part only (8 planes); rows 2-15 zeroed once.
// Predicted: ~955us (1176 x ~1950cyc), WRITE=12800 exactly (spill check),
// MfmaUtil ~30%, VALUBusy ~45%, occupancy ~24%.
// Numerics: W1/W2 hi fp16 (W1 prescaled 2*log2e), u fp32, fp32 state,
// tanh = 1 - 2*rcp(exp2(y)+1); absmax floor 0.0156 (thresh 0.105).
// MFMA layouts (HW-verified R7/R8): A[m=l&15][k=(l>>4)*8+j],
//   B[k=(l>>4)*8+j][n=l&15], D[row=(l>>4)*4+reg][col=l&15].
// A-frag LDS planes [k>>3][m][k&7], stride 144 halves (288B).

typedef _Float16 half8 __attribute__((ext_vector_type(8)));
typedef float f32x4 __attribute__((ext_vector_type(4)));

#define MFMA16(a, b, c) __builtin_amdgcn_mfma_f32_16x16x32_f16((a), (b), (c), 0, 0, 0)

__global__ __launch_bounds__(256, 2)
void node_kernel(const float* __restrict__ x0,
                 const float* __restrict__ t_eval,
                 const float* __restrict__ t_u,
                 const float* __restrict__ u_batch,
                 const float* __restrict__ W1,
                 const float* __restrict__ b1,
                 const float* __restrict__ W2,
                 const float* __restrict__ b2,
                 float* __restrict__ out)
{
    __shared__ __align__(16) _Float16 zAh[8 * 144];    // z x-part, K=64
    __shared__ __align__(16) _Float16 hAh[32 * 144];   // h, K=256
    __shared__ __align__(16) float ush[6][2][8];       // interp u /stage/row

    const int tid = threadIdx.x;
    const int wv  = tid >> 6;        // wave 0..3
    const int l   = tid & 63;
    const int lm  = l & 15;
    const int lq  = l >> 4;
    const int blk = blockIdx.x;

    const float C2L = 2.8853900817779268f;   // 2*log2(e)

    // --- zero zAh/hAh once: padding rows stay 0 forever ---
    for (int i = tid; i < (8 * 144) / 2; i += 256)  ((uint32_t*)zAh)[i] = 0u;
    for (int i = tid; i < (32 * 144) / 2; i += 256) ((uint32_t*)hAh)[i] = 0u;

    // --- GEMM1 B-frags: wave owns N-tiles wv*4+t, x-part K=64 only ---
    half8 b1h[4][2];
    float b1b[4];
#pragma unroll
    for (int t = 0; t < 4; ++t) {
        const int n1 = (wv * 4 + t) * 16 + lm;
        b1b[t] = b1[n1] * C2L;
#pragma unroll
        for (int c = 0; c < 2; ++c) {
#pragma unroll
            for (int j = 0; j < 8; ++j) {
                const int k = c * 32 + lq * 8 + j;
                b1h[t][c][j] = (_Float16)(W1[k * 256 + n1] * C2L);
            }
        }
    }
    // --- u-part weights: lane l holds W1u[f][wv*64+l], f=0..7 (fp32) ---
    const int n1u = wv * 64 + l;
    float w1u[8];
#pragma unroll
    for (int f = 0; f < 8; ++f)
        w1u[f] = W1[(64 + f) * 256 + n1u] * C2L;

    // --- GEMM2 B-frags: wave owns N-tile wv, FULL K=256 ---
    const int n2 = wv * 16 + lm;
    half8 b2h[8];
#pragma unroll
    for (int cc = 0; cc < 8; ++cc) {
#pragma unroll
        for (int j = 0; j < 8; ++j) {
            const int k = cc * 32 + lq * 8 + j;
            b2h[cc][j] = (_Float16)W2[k * 64 + n2];
        }
    }
    const float b2b = b2[n2];

    // --- ODE state: rows 0,1 <-> regs 0,1 of lq==0 lanes. All lanes carry
    //     copies; only lq==0 lanes publish. ---
    float xr[2];
    float kfr[5][2];
#pragma unroll
    for (int r = 0; r < 2; ++r) {
        const int gr = blk * 2 + r;
        xr[r] = x0[gr * 64 + n2];
        if (lq == 0) out[gr * 3200 + n2] = xr[r];      // t_eval[0]
    }
    __syncthreads();   // zero-init visible

#pragma unroll 1
    for (int step = 0; step < 196; ++step) {
        const int n = step >> 2;
        const int m = step & 3;
        const float te0 = t_eval[n];
        const float dtc = t_eval[n + 1] - te0;
        const float t   = te0 + dtc * (0.25f * (float)m);
        const float dt  = dtc * 0.25f;

        // --- u prefetch+interp: 96 slots (6 stages x 2 rows x 8 feats) ---
        if (tid < 96) {
            const int s   = tid >> 4;
            const int rem = tid & 15;
            const int mr  = rem >> 3, f = rem & 7;
            float cs;
            switch (s) {
                case 0: cs = 0.0f; break;
                case 1: cs = 1.0f / 5.0f; break;
                case 2: cs = 3.0f / 10.0f; break;
                case 3: cs = 4.0f / 5.0f; break;
                case 4: cs = 8.0f / 9.0f; break;
                default: cs = 1.0f; break;
            }
            const float tsv = t + dt * cs;
            int iu = (int)(tsv * 127.0f);       // == searchsorted-1
            iu = iu < 0 ? 0 : (iu > 126 ? 126 : iu);
            const float ta = t_u[iu];
            const float tb = t_u[iu + 1];
            const float wt = (tsv - ta) / (tb - ta);
            const float* ub = &u_batch[(blk * 2 + mr) * 1024 + iu * 8 + f];
            const float u0v = ub[0];
            const float u1v = ub[8];
            ush[s][mr][f] = fmaf(wt, u1v - u0v, u0v);
        }
        __syncthreads();   // B0: ush ready

#pragma unroll
        for (int s = 0; s < 6; ++s) {
            // --- z x-part rows 0,1 (combine in all lanes, lq==0 writes) ---
            float zv[2];
#pragma unroll
            for (int r = 0; r < 2; ++r) {
                float v;
                if (s == 0)      v = xr[r];
                else if (s == 1) v = fmaf(dt, kfr[0][r] * (1.0f/5.0f), xr[r]);
                else if (s == 2) v = fmaf(dt, fmaf(3.0f/40.0f, kfr[0][r], (9.0f/40.0f)*kfr[1][r]), xr[r]);
                else if (s == 3) v = fmaf(dt, (44.0f/45.0f)*kfr[0][r] + (-56.0f/15.0f)*kfr[1][r]
                                             + (32.0f/9.0f)*kfr[2][r], xr[r]);
                else if (s == 4) v = fmaf(dt, (19372.0f/6561.0f)*kfr[0][r] + (-25360.0f/2187.0f)*kfr[1][r]
                                             + (64448.0f/6561.0f)*kfr[2][r] + (-212.0f/729.0f)*kfr[3][r], xr[r]);
                else             v = fmaf(dt, (9017.0f/3168.0f)*kfr[0][r] + (-355.0f/33.0f)*kfr[1][r]
                                             + (46732.0f/5247.0f)*kfr[2][r] + (49.0f/176.0f)*kfr[3][r]
                                             + (-5103.0f/18656.0f)*kfr[4][r], xr[r]);
                zv[r] = v;
            }
            if (lq == 0) {
#pragma unroll
                for (int r = 0; r < 2; ++r)
                    zAh[(n2 >> 3) * 144 + r * 8 + (n2 & 7)] = (_Float16)zv[r];
            }
            __syncthreads();   // B1: z ready

            // --- u-part rank-8 dot per row: y_u for col wv*64 + l ---
            const float4 uA0 = *(const float4*)&ush[s][0][0];
            const float4 uB0 = *(const float4*)&ush[s][0][4];
            const float4 uA1 = *(const float4*)&ush[s][1][0];
            const float4 uB1 = *(const float4*)&ush[s][1][4];
            float yu0 = uA0.x * w1u[0];
            yu0 = fmaf(uA0.y, w1u[1], yu0);
            yu0 = fmaf(uA0.z, w1u[2], yu0);
            yu0 = fmaf(uA0.w, w1u[3], yu0);
            yu0 = fmaf(uB0.x, w1u[4], yu0);
            yu0 = fmaf(uB0.y, w1u[5], yu0);
            yu0 = fmaf(uB0.z, w1u[6], yu0);
            yu0 = fmaf(uB0.w, w1u[7], yu0);
            float yu1 = uA1.x * w1u[0];
            yu1 = fmaf(uA1.y, w1u[1], yu1);
            yu1 = fmaf(uA1.z, w1u[2], yu1);
            yu1 = fmaf(uA1.w, w1u[3], yu1);
            yu1 = fmaf(uB1.x, w1u[4], yu1);
            yu1 = fmaf(uB1.y, w1u[5], yu1);
            yu1 = fmaf(uB1.z, w1u[6], yu1);
            yu1 = fmaf(uB1.w, w1u[7], yu1);

            // --- GEMM1: 2 A-reads, 4 N-tiles, 8 MFMAs ---
            half8 az[2];
#pragma unroll
            for (int c = 0; c < 2; ++c)
                az[c] = *(const half8*)&zAh[(c * 4 + lq) * 144 + lm * 8];
#pragma unroll
            for (int t = 0; t < 4; ++t) {
                f32x4 aHH = {0.f, 0.f, 0.f, 0.f};
                aHH = MFMA16(az[0], b1h[t][0], aHH);
                aHH = MFMA16(az[1], b1h[t][1], aHH);
                const float yut0 = __shfl(yu0, t * 16 + lm);
                const float yut1 = __shfl(yu1, t * 16 + lm);
                const int kqb = (wv * 4 + t) * 2 + (lm >> 3);   // h-col>>3 plane
                // tanh rows 0,1 (regs 0,1; valid in lq==0 lanes)
                const float y0 = aHH[0] + yut0 + b1b[t];         // 2log2e*(zW1+b1)
                const float y1 = aHH[1] + yut1 + b1b[t];
                const float e0 = __builtin_amdgcn_exp2f(y0);
                const float e1 = __builtin_amdgcn_exp2f(y1);
                const float h0 = fmaf(-2.0f, __builtin_amdgcn_rcpf(e0 + 1.0f), 1.0f);
                const float h1 = fmaf(-2.0f, __builtin_amdgcn_rcpf(e1 + 1.0f), 1.0f);
                if (lq == 0) {
                    hAh[kqb * 144 + (lm & 7)]     = (_Float16)h0;
                    hAh[kqb * 144 + 8 + (lm & 7)] = (_Float16)h1;
                }
            }
            __syncthreads();   // B2: h ready

            // --- GEMM2: full K=256, 8 MFMAs in 2 dep-chains of 4 ---
            f32x4 aP = {0.f, 0.f, 0.f, 0.f};
            f32x4 aR = {0.f, 0.f, 0.f, 0.f};
#pragma unroll
            for (int cc = 0; cc < 8; cc += 2) {
                const half8 ah0 = *(const half8*)&hAh[((cc    ) * 4 + lq) * 144 + lm * 8];
                const half8 ah1 = *(const half8*)&hAh[((cc + 1) * 4 + lq) * 144 + lm * 8];
                aP = MFMA16(ah0, b2h[cc    ], aP);
                aR = MFMA16(ah1, b2h[cc + 1], aR);
            }
            if (s < 5) {
#pragma unroll
                for (int r = 0; r < 2; ++r)
                    kfr[s][r] = (aP[r] + aR[r]) + b2b;
            } else {
#pragma unroll
                for (int r = 0; r < 2; ++r) {
                    const float k6 = (aP[r] + aR[r]) + b2b;
                    xr[r] = fmaf(dt, (35.0f/384.0f)*kfr[0][r] + (500.0f/1113.0f)*kfr[2][r]
                                    + (125.0f/192.0f)*kfr[3][r] + (-2187.0f/6784.0f)*kfr[4][r]
                                    + (11.0f/84.0f)*k6, xr[r]);
                }
            }
        }

        // --- output every 4th substep ---
        if (m == 3 && lq == 0) {
#pragma unroll
            for (int r = 0; r < 2; ++r)
                out[(blk * 2 + r) * 3200 + (n + 1) * 64 + n2] = xr[r];
        }
    }
}

extern "C" void kernel_launch(void* const* d_in, const int* in_sizes, int n_in,
                              void* d_out, int out_size, void* d_ws, size_t ws_size,
                              hipStream_t stream) {
    const float* x0      = (const float*)d_in[0];
    const float* t_eval  = (const float*)d_in[1];
    const float* t_u     = (const float*)d_in[2];
    const float* u_batch = (const float*)d_in[3];
    const float* W1      = (const float*)d_in[4];
    const float* b1      = (const float*)d_in[5];
    const float* W2      = (const float*)d_in[6];
    const float* b2      = (const float*)d_in[7];
    float* out = (float*)d_out;

    node_kernel<<<dim3(512), dim3(256), 0, stream>>>(
        x0, t_eval, t_u, u_batch, W1, b1, W2, b2, out);
}

// Round 7
// 1011.387 us; speedup vs baseline: 1.7363x; 1.1471x over previous
//
#include <hip/hip_runtime.h>

// NeuralODE: B=1024, D=64, F=8, H=256, 196 substeps x 6 dopri5 stages.
// R16: compressed 3-row LDS + u back on the MFMA pipe. 512 blocks x 256
// threads, 2 rows/block, launch_bounds(256,2) (proven clean: no spill).
// R15 ledger (stage=2367cyc): LDS pipe ~54% busy (640cyc A-reads + 320cyc
// BANK CONFLICTS per CU-stage), VALU 42%, MFMA 23%. 87% of A-read traffic
// was zero padding rows (M=16 tile, 2 real rows); 8 __shfl/wave sat in
// GEMM1's dependency path. R16:
//  - Planes stored [row0 16B][row1 16B][zero 16B], stride 48B. Lanes lm>=2
//    read the plane's zero block -> same-address broadcast (free). Per
//    b128 read: 12 distinct 16B chunks; 48B (12-dword) plane stride makes
//    4-plane groups cover all 32 banks -> ~2 phases vs 8, conflicts ~0.
//    rowoff = min(lm,2)*16 is loop-invariant; reads = base + imm offset.
//  - u-part back in z plane 8 (fp16, as R10/R11: same 0.0156 absmax):
//    GEMM1 = 3 A-frags, 12 MFMAs; kills 8 bpermute + 16 fmaf from the
//    critical path. MFMA pipe had 77% headroom.
// MFMA layouts (HW-verified R7/R8): A[m=l&15][k=(l>>4)*8+j],
//   B[k=(l>>4)*8+j][n=l&15], D[row=(l>>4)*4+reg][col=l&15].
// Numerics: W1/W2 hi fp16 (W1 prescaled 2*log2e), fp32 state+combine,
// tanh = 1 - 2*rcp(exp2(y)+1); absmax floor 0.0156 (thresh 0.105).

typedef _Float16 half8 __attribute__((ext_vector_type(8)));
typedef float f32x4 __attribute__((ext_vector_type(4)));

#define MFMA16(a, b, c) __builtin_amdgcn_mfma_f32_16x16x32_f16((a), (b), (c), 0, 0, 0)

__global__ __launch_bounds__(256, 2)
void node_kernel(const float* __restrict__ x0,
                 const float* __restrict__ t_eval,
                 const float* __restrict__ t_u,
                 const float* __restrict__ u_batch,
                 const float* __restrict__ W1,
                 const float* __restrict__ b1,
                 const float* __restrict__ W2,
                 const float* __restrict__ b2,
                 float* __restrict__ out)
{
    // plane = 24 halves (48B): [row0 x8][row1 x8][zeros x8]
    __shared__ __align__(16) _Float16 zAh[12 * 24];    // z: planes 0..7 x-part,
                                                       // 8 u, 9..11 K-pad
    __shared__ __align__(16) _Float16 hAh[32 * 24];    // h: K=256
    __shared__ __align__(16) float ush[6][2][8];       // interp u /stage/row

    const int tid = threadIdx.x;
    const int wv  = tid >> 6;        // wave 0..3
    const int l   = tid & 63;
    const int lm  = l & 15;
    const int lq  = l >> 4;
    const int blk = blockIdx.x;

    const float C2L = 2.8853900817779268f;   // 2*log2(e)

    // --- zero zAh/hAh once: zero blocks + pad planes stay 0 forever ---
    for (int i = tid; i < (12 * 24) / 2; i += 256) ((uint32_t*)zAh)[i] = 0u;
    for (int i = tid; i < (32 * 24) / 2; i += 256) ((uint32_t*)hAh)[i] = 0u;

    // --- A-read base: lane lm>=2 -> plane's zero block (broadcast) ---
    const int rowoff = (lm < 2 ? lm : 2) * 16;               // bytes
    const char* zb = (const char*)zAh + lq * 48 + rowoff;
    const char* hb = (const char*)hAh + lq * 48 + rowoff;

    // --- GEMM1 B-frags: wave owns N-tiles wv*4+t, K=96 (72 real) ---
    half8 b1h[4][3];
    float b1b[4];
#pragma unroll
    for (int t = 0; t < 4; ++t) {
        const int n1 = (wv * 4 + t) * 16 + lm;
        b1b[t] = b1[n1] * C2L;
#pragma unroll
        for (int c = 0; c < 3; ++c) {
#pragma unroll
            for (int j = 0; j < 8; ++j) {
                const int k = c * 32 + lq * 8 + j;
                b1h[t][c][j] = (_Float16)((k < 72) ? W1[k * 256 + n1] * C2L : 0.0f);
            }
        }
    }

    // --- GEMM2 B-frags: wave owns N-tile wv, FULL K=256 ---
    const int n2 = wv * 16 + lm;
    half8 b2h[8];
#pragma unroll
    for (int cc = 0; cc < 8; ++cc) {
#pragma unroll
        for (int j = 0; j < 8; ++j) {
            const int k = cc * 32 + lq * 8 + j;
            b2h[cc][j] = (_Float16)W2[k * 64 + n2];
        }
    }
    const float b2b = b2[n2];

    // --- ODE state: rows 0,1 <-> regs 0,1 of lq==0 lanes. All lanes carry
    //     copies; only lq==0 lanes publish. ---
    float xr[2];
    float kfr[5][2];
#pragma unroll
    for (int r = 0; r < 2; ++r) {
        const int gr = blk * 2 + r;
        xr[r] = x0[gr * 64 + n2];
        if (lq == 0) out[gr * 3200 + n2] = xr[r];      // t_eval[0]
    }
    __syncthreads();   // zero-init visible

#pragma unroll 1
    for (int step = 0; step < 196; ++step) {
        const int n = step >> 2;
        const int m = step & 3;
        const float te0 = t_eval[n];
        const float dtc = t_eval[n + 1] - te0;
        const float t   = te0 + dtc * (0.25f * (float)m);
        const float dt  = dtc * 0.25f;

        // --- u prefetch+interp: 96 slots (6 stages x 2 rows x 8 feats) ---
        if (tid < 96) {
            const int s   = tid >> 4;
            const int rem = tid & 15;
            const int mr  = rem >> 3, f = rem & 7;
            float cs;
            switch (s) {
                case 0: cs = 0.0f; break;
                case 1: cs = 1.0f / 5.0f; break;
                case 2: cs = 3.0f / 10.0f; break;
                case 3: cs = 4.0f / 5.0f; break;
                case 4: cs = 8.0f / 9.0f; break;
                default: cs = 1.0f; break;
            }
            const float tsv = t + dt * cs;
            int iu = (int)(tsv * 127.0f);       // == searchsorted-1
            iu = iu < 0 ? 0 : (iu > 126 ? 126 : iu);
            const float ta = t_u[iu];
            const float tb = t_u[iu + 1];
            const float wt = (tsv - ta) / (tb - ta);
            const float* ub = &u_batch[(blk * 2 + mr) * 1024 + iu * 8 + f];
            const float u0v = ub[0];
            const float u1v = ub[8];
            ush[s][mr][f] = fmaf(wt, u1v - u0v, u0v);
        }
        __syncthreads();   // B0: ush ready

#pragma unroll
        for (int s = 0; s < 6; ++s) {
            // --- z x-part rows 0,1 (combine in all lanes, lq==0 writes) ---
            float zv[2];
#pragma unroll
            for (int r = 0; r < 2; ++r) {
                float v;
                if (s == 0)      v = xr[r];
                else if (s == 1) v = fmaf(dt, kfr[0][r] * (1.0f/5.0f), xr[r]);
                else if (s == 2) v = fmaf(dt, fmaf(3.0f/40.0f, kfr[0][r], (9.0f/40.0f)*kfr[1][r]), xr[r]);
                else if (s == 3) v = fmaf(dt, (44.0f/45.0f)*kfr[0][r] + (-56.0f/15.0f)*kfr[1][r]
                                             + (32.0f/9.0f)*kfr[2][r], xr[r]);
                else if (s == 4) v = fmaf(dt, (19372.0f/6561.0f)*kfr[0][r] + (-25360.0f/2187.0f)*kfr[1][r]
                                             + (64448.0f/6561.0f)*kfr[2][r] + (-212.0f/729.0f)*kfr[3][r], xr[r]);
                else             v = fmaf(dt, (9017.0f/3168.0f)*kfr[0][r] + (-355.0f/33.0f)*kfr[1][r]
                                             + (46732.0f/5247.0f)*kfr[2][r] + (49.0f/176.0f)*kfr[3][r]
                                             + (-5103.0f/18656.0f)*kfr[4][r], xr[r]);
                zv[r] = v;
            }
            if (lq == 0) {
#pragma unroll
                for (int r = 0; r < 2; ++r)
                    zAh[(n2 >> 3) * 24 + r * 8 + (n2 & 7)] = (_Float16)zv[r];
            }
            // --- wave 1, lanes 0-7: z u-part (plane 8), dword-packed ---
            if (wv == 1 && l < 8) {
                const int mm = l >> 2;              // row 0,1
                const int jj = (l & 3) * 2;
                const _Float16 u0h = (_Float16)ush[s][mm][jj];
                const _Float16 u1h = (_Float16)ush[s][mm][jj + 1];
                uint32_t pk = (uint32_t)*(const uint16_t*)&u0h
                            | ((uint32_t)*(const uint16_t*)&u1h << 16);
                *(uint32_t*)&zAh[8 * 24 + mm * 8 + jj] = pk;
            }
            __syncthreads();   // B1: z ready

            // --- GEMM1: 3 A-reads (compressed planes), 4 N-tiles, 12 MFMAs ---
            const half8 az0 = *(const half8*)(zb);
            const half8 az1 = *(const half8*)(zb + 192);
            const half8 az2 = *(const half8*)(zb + 384);
#pragma unroll
            for (int t = 0; t < 4; ++t) {
                f32x4 aHH = {0.f, 0.f, 0.f, 0.f};
                aHH = MFMA16(az0, b1h[t][0], aHH);
                aHH = MFMA16(az1, b1h[t][1], aHH);
                aHH = MFMA16(az2, b1h[t][2], aHH);
                const int pl = (wv * 4 + t) * 2 + (lm >> 3);   // h-plane
                // tanh rows 0,1 (regs 0,1; valid in lq==0 lanes)
                const float y0 = aHH[0] + b1b[t];              // 2log2e*(zW1+b1)
                const float y1 = aHH[1] + b1b[t];
                const float e0 = __builtin_amdgcn_exp2f(y0);
                const float e1 = __builtin_amdgcn_exp2f(y1);
                const float h0 = fmaf(-2.0f, __builtin_amdgcn_rcpf(e0 + 1.0f), 1.0f);
                const float h1 = fmaf(-2.0f, __builtin_amdgcn_rcpf(e1 + 1.0f), 1.0f);
                if (lq == 0) {
                    hAh[pl * 24 + (lm & 7)]     = (_Float16)h0;
                    hAh[pl * 24 + 8 + (lm & 7)] = (_Float16)h1;
                }
            }
            __syncthreads();   // B2: h ready

            // --- GEMM2: full K=256, 8 MFMAs in 2 dep-chains of 4 ---
            f32x4 aP = {0.f, 0.f, 0.f, 0.f};
            f32x4 aR = {0.f, 0.f, 0.f, 0.f};
#pragma unroll
            for (int cc = 0; cc < 8; cc += 2) {
                const half8 ah0 = *(const half8*)(hb + cc * 192);
                const half8 ah1 = *(const half8*)(hb + cc * 192 + 192);
                aP = MFMA16(ah0, b2h[cc    ], aP);
                aR = MFMA16(ah1, b2h[cc + 1], aR);
            }
            if (s < 5) {
#pragma unroll
                for (int r = 0; r < 2; ++r)
                    kfr[s][r] = (aP[r] + aR[r]) + b2b;
            } else {
#pragma unroll
                for (int r = 0; r < 2; ++r) {
                    const float k6 = (aP[r] + aR[r]) + b2b;
                    xr[r] = fmaf(dt, (35.0f/384.0f)*kfr[0][r] + (500.0f/1113.0f)*kfr[2][r]
                                    + (125.0f/192.0f)*kfr[3][r] + (-2187.0f/6784.0f)*kfr[4][r]
                                    + (11.0f/84.0f)*k6, xr[r]);
                }
            }
        }

        // --- output every 4th substep ---
        if (m == 3 && lq == 0) {
#pragma unroll
            for (int r = 0; r < 2; ++r)
                out[(blk * 2 + r) * 3200 + (n + 1) * 64 + n2] = xr[r];
        }
    }
}

extern "C" void kernel_launch(void* const* d_in, const int* in_sizes, int n_in,
                              void* d_out, int out_size, void* d_ws, size_t ws_size,
                              hipStream_t stream) {
    const float* x0      = (const float*)d_in[0];
    const float* t_eval  = (const float*)d_in[1];
    const float* t_u     = (const float*)d_in[2];
    const float* u_batch = (const float*)d_in[3];
    const float* W1      = (const float*)d_in[4];
    const float* b1      = (const float*)d_in[5];
    const float* W2      = (const float*)d_in[6];
    const float* b2      = (const float*)d_in[7];
    float* out = (float*)d_out;

    node_kernel<<<dim3(512), dim3(256), 0, stream>>>(
        x0, t_eval, t_u, u_batch, W1, b1, W2, b2, out);
}